// Round 4
// baseline (10525.092 us; speedup 1.0000x reference)
//
#include <hip/hip_runtime.h>

// VQ nearest-codebook, fp32. z-in-SGPR / e-in-LDS, register-budgeted.
// score(n,k) = 0.5*|e_k|^2 - z_n.e_k (monotone in squared distance)
//
// vq_main: grid = (N/64 token-blocks) x 16 K-splits. 4 waves/block; each
//   wave owns 16 tokens (wave-uniform z -> SGPR) and all 512 codes of the
//   split (8 per lane). acc[16][8] = 128 VGPR persists across the c loop.
//   LDS: e-chunk [4 f4][512 codes] (32 KB), staged once per 16-c step with
//   lane-pair-consecutive writes (2-way = free) and 64B-complete global
//   reads; double-buffered via 8 prefetch VGPRs. Inner loop: 8 ds_read_b128
//   per 4-c quarter, each feeding 16 tokens x 4 c = 64 FMAs.
// vq_final: combine 16 split candidates per token, gather embedding row.

#define C 256
#define C4 64            // float4 per row
#define TPB 256
#define WT 16            // tokens per wave
#define BT 64            // tokens per block
#define BC 512           // codes per block/split
#define NSPLIT 16
#define NST 16           // staging steps: 256 c / 16 c

__global__ __launch_bounds__(64) void vq_norms(const float* __restrict__ emb,
                                               float* __restrict__ hn) {
    const int k = blockIdx.x;
    const int lane = threadIdx.x;
    const float4 v = *reinterpret_cast<const float4*>(emb + (size_t)k * C + lane * 4);
    float s = v.x * v.x + v.y * v.y + v.z * v.z + v.w * v.w;
    #pragma unroll
    for (int off = 32; off; off >>= 1) s += __shfl_down(s, off);
    if (lane == 0) hn[k] = 0.5f * s;
}

__global__ __launch_bounds__(TPB, 2) void vq_main(
    const float* __restrict__ z, const float* __restrict__ emb,
    const float* __restrict__ hn, float* __restrict__ bs,
    int* __restrict__ bia, int Ntok) {
    __shared__ float4 et[4][BC];   // 32 KB

    const int tid = threadIdx.x;
    const int lane = tid & 63;
    const int wid = __builtin_amdgcn_readfirstlane(tid >> 6);
    const int sp = blockIdx.x & (NSPLIT - 1);
    const int tb = blockIdx.x >> 4;
    const int cbase = sp * BC;
    const int token0 = tb * BT + wid * WT;
    const float* zw = z + (size_t)token0 * C;          // wave-uniform
    const float4* ef4 = reinterpret_cast<const float4*>(emb);

    // staging geometry: lane pairs cover 64B of one code row
    const int scode = tid >> 1;          // 0..127 (+128*p)
    const int sq0 = (tid & 1) * 2;       // f4 quarter base 0 or 2

    float4 pf[4][2];
    #pragma unroll
    for (int p = 0; p < 4; ++p)
        #pragma unroll
        for (int i = 0; i < 2; ++i)
            pf[p][i] = ef4[(size_t)(cbase + scode + 128 * p) * C4 + sq0 + i];

    float acc[WT][8] = {};

    #pragma unroll 1
    for (int st = 0; st < NST; ++st) {
        __syncthreads();
        #pragma unroll
        for (int p = 0; p < 4; ++p)
            #pragma unroll
            for (int i = 0; i < 2; ++i)
                et[sq0 + i][scode + 128 * p] = pf[p][i];
        if (st + 1 < NST) {
            #pragma unroll
            for (int p = 0; p < 4; ++p)
                #pragma unroll
                for (int i = 0; i < 2; ++i)
                    pf[p][i] = ef4[(size_t)(cbase + scode + 128 * p) * C4 +
                                   (st + 1) * 4 + sq0 + i];
        }
        __syncthreads();

        #pragma unroll
        for (int cq = 0; cq < 4; ++cq) {
            float4 ev[8];
            #pragma unroll
            for (int m = 0; m < 8; ++m) ev[m] = et[cq][m * 64 + lane];
            // tokens 0..7: z held in SGPRs
            float4 za[8];
            #pragma unroll
            for (int j = 0; j < 8; ++j)
                za[j] = *reinterpret_cast<const float4*>(
                    zw + j * C + st * 16 + cq * 4);
            #pragma unroll
            for (int j = 0; j < 8; ++j) {
                #pragma unroll
                for (int m = 0; m < 8; ++m) {
                    acc[j][m] = fmaf(za[j].x, ev[m].x, acc[j][m]);
                    acc[j][m] = fmaf(za[j].y, ev[m].y, acc[j][m]);
                    acc[j][m] = fmaf(za[j].z, ev[m].z, acc[j][m]);
                    acc[j][m] = fmaf(za[j].w, ev[m].w, acc[j][m]);
                }
            }
            // tokens 8..15: transient per-token z scalar
            #pragma unroll
            for (int j = 8; j < 16; ++j) {
                const float4 zj = *reinterpret_cast<const float4*>(
                    zw + j * C + st * 16 + cq * 4);
                #pragma unroll
                for (int m = 0; m < 8; ++m) {
                    acc[j][m] = fmaf(zj.x, ev[m].x, acc[j][m]);
                    acc[j][m] = fmaf(zj.y, ev[m].y, acc[j][m]);
                    acc[j][m] = fmaf(zj.z, ev[m].z, acc[j][m]);
                    acc[j][m] = fmaf(zj.w, ev[m].w, acc[j][m]);
                }
            }
        }
    }

    // epilogue: per-token argmin over this wave's 512 codes
    float hv[8];
    #pragma unroll
    for (int m = 0; m < 8; ++m) hv[m] = hn[cbase + m * 64 + lane];

    #pragma unroll 1
    for (int j = 0; j < WT; ++j) {
        float s = 3.4e38f;
        int bi = 0;
        #pragma unroll
        for (int m = 0; m < 8; ++m) {   // ascending code within lane
            const float sc = hv[m] - acc[j][m];
            const int code = cbase + m * 64 + lane;
            if (sc < s) { s = sc; bi = code; }
        }
        #pragma unroll
        for (int off = 32; off; off >>= 1) {
            const float os = __shfl_xor(s, off);
            const int oi = __shfl_xor(bi, off);
            if (os < s || (os == s && oi < bi)) { s = os; bi = oi; }
        }
        if (lane == 0) {
            const int token = token0 + j;
            bs[sp * Ntok + token] = s;
            bia[sp * Ntok + token] = bi;
        }
    }
}

__global__ __launch_bounds__(256) void vq_final(const float* __restrict__ emb,
                                                const float* __restrict__ bs,
                                                const int* __restrict__ bia,
                                                float* __restrict__ out, int Ntok) {
    const int token = blockIdx.x * 4 + (threadIdx.x >> 6);
    const int lane = threadIdx.x & 63;
    float best = 3.4e38f;
    int b = 0;
    #pragma unroll
    for (int s = 0; s < NSPLIT; ++s) {   // ascending split = ascending codes
        const float sc = bs[s * Ntok + token];
        const int ii = bia[s * Ntok + token];
        if (sc < best) { best = sc; b = ii; }
    }
    const float4* ef4 = reinterpret_cast<const float4*>(emb);
    float4* of4 = reinterpret_cast<float4*>(out);
    of4[(size_t)token * C4 + lane] = ef4[(size_t)b * C4 + lane];
}

extern "C" void kernel_launch(void* const* d_in, const int* in_sizes, int n_in,
                              void* d_out, int out_size, void* d_ws, size_t ws_size,
                              hipStream_t stream) {
    const float* z = (const float*)d_in[0];
    const float* emb = (const float*)d_in[1];
    float* out = (float*)d_out;

    const int N = in_sizes[0] / C;   // 16384 tokens
    const int K = in_sizes[1] / C;   // 8192 codes

    float* hn = (float*)d_ws;                 // K floats
    float* bs = hn + K;                       // NSPLIT*N floats
    int* bia = (int*)(bs + NSPLIT * N);       // NSPLIT*N ints (~2.1 MB total)

    vq_norms<<<K, 64, 0, stream>>>(emb, hn);
    vq_main<<<(N / BT) * NSPLIT, TPB, 0, stream>>>(z, emb, hn, bs, bia, N);
    vq_final<<<N / 4, 256, 0, stream>>>(emb, bs, bia, out, N);
}

// Round 5
// 1360.783 us; speedup vs baseline: 7.7346x; 7.7346x over previous
//
#include <hip/hip_runtime.h>

// VQ nearest-codebook, fp32, z-in-SGPR / e-in-LDS design (round-3 structure,
// scratch-spill bug fixed: ALL accumulator indices compile-time-static).
// score(n,k) = 0.5*|e_k|^2 - z_n.e_k  (monotone in squared distance)
//
// vq_main: block = 32 tokens x 512 codes (16 K-splits). 4 waves; each wave
//   owns 8 tokens (wave-uniform -> z via s_load into SGPRs) and all 512
//   codes (8 per lane). acc[8][8] persists across the full c loop.
//   LDS holds only the e-chunk [2 f4][512 codes], double-buffered; all LDS
//   ops lane-consecutive float4 (conflict-free; verified 0 in round 3).
// vq_final: combine 16 split candidates per token, gather embedding row.

#define C 256
#define C4 64            // float4 per row
#define TPB 256
#define BT 32            // tokens per block
#define WT 8             // tokens per wave
#define BC 512           // codes per block (one per-lane x 8 groups)
#define NSPLIT 16
#define NCK 32           // 256 c / 8 c per chunk

__global__ __launch_bounds__(64) void vq_norms(const float* __restrict__ emb,
                                               float* __restrict__ hn) {
    const int k = blockIdx.x;
    const int lane = threadIdx.x;
    const float4 v = *reinterpret_cast<const float4*>(emb + (size_t)k * C + lane * 4);
    float s = v.x * v.x + v.y * v.y + v.z * v.z + v.w * v.w;
    #pragma unroll
    for (int off = 32; off; off >>= 1) s += __shfl_down(s, off);
    if (lane == 0) hn[k] = 0.5f * s;
}

__device__ __forceinline__ void fma8(float (&acc)[WT][8], int m,
                                     const float4 (&zs)[WT], const float4 ev) {
    #pragma unroll
    for (int j = 0; j < WT; ++j) {
        acc[j][m] = fmaf(zs[j].x, ev.x, acc[j][m]);
        acc[j][m] = fmaf(zs[j].y, ev.y, acc[j][m]);
        acc[j][m] = fmaf(zs[j].z, ev.z, acc[j][m]);
        acc[j][m] = fmaf(zs[j].w, ev.w, acc[j][m]);
    }
}

__global__ __launch_bounds__(TPB, 2) void vq_main(
    const float* __restrict__ z, const float* __restrict__ emb,
    const float* __restrict__ hn, float* __restrict__ bs,
    int* __restrict__ bia, int Ntok) {
    __shared__ float4 et[2][2][BC];   // [buf][f4-half][code]  32 KB

    const int tid = threadIdx.x;
    const int lane = tid & 63;
    const int wid = __builtin_amdgcn_readfirstlane(tid >> 6);
    const int sp = blockIdx.x & (NSPLIT - 1);
    const int tb = blockIdx.x >> 4;
    const int cbase = sp * BC;
    const int token0 = tb * BT + wid * WT;
    const float* zw = z + (size_t)token0 * C;             // wave-uniform
    const float4* ef4 = reinterpret_cast<const float4*>(emb);

    // stage chunk 0
    #pragma unroll
    for (int it = 0; it < 2; ++it) {
        const int code = it * TPB + tid;
        const float4* g = ef4 + (size_t)(cbase + code) * C4;
        et[0][0][code] = g[0];
        et[0][1][code] = g[1];
    }
    __syncthreads();

    float acc[WT][8] = {};

    #pragma unroll 2
    for (int ck = 0; ck < NCK; ++ck) {
        const int nb = ck & 1;
        // prefetch next e-chunk into registers
        float4 ra[2], rb[2];
        if (ck < NCK - 1) {
            #pragma unroll
            for (int it = 0; it < 2; ++it) {
                const int code = it * TPB + tid;
                const float4* g = ef4 + (size_t)(cbase + code) * C4 + (ck + 1) * 2;
                ra[it] = g[0];
                rb[it] = g[1];
            }
        }
        // z scalars for this chunk (wave-uniform -> s_load)
        float4 za[WT], zb[WT];
        #pragma unroll
        for (int j = 0; j < WT; ++j) {
            const float4* p = reinterpret_cast<const float4*>(zw + j * C) + ck * 2;
            za[j] = p[0];
            zb[j] = p[1];
        }
        // compute: 2 f4-halves x 8 code-groups x 8 tokens x 4 c
        #pragma unroll
        for (int m = 0; m < 8; ++m) fma8(acc, m, za, et[nb][0][m * 64 + lane]);
        #pragma unroll
        for (int m = 0; m < 8; ++m) fma8(acc, m, zb, et[nb][1][m * 64 + lane]);

        if (ck < NCK - 1) {
            #pragma unroll
            for (int it = 0; it < 2; ++it) {
                const int code = it * TPB + tid;
                et[nb ^ 1][0][code] = ra[it];
                et[nb ^ 1][1][code] = rb[it];
            }
        }
        __syncthreads();
    }

    // epilogue: per-token argmin over this wave's 512 codes.
    // FULLY UNROLLED: every acc/best index is compile-time-constant
    // (runtime indexing here was the round-3/4 scratch-spill bug).
    float hv[8];
    #pragma unroll
    for (int m = 0; m < 8; ++m) hv[m] = hn[cbase + m * 64 + lane];

    #pragma unroll
    for (int j = 0; j < WT; ++j) {
        float s = 3.4e38f;
        int bi = 0;
        #pragma unroll
        for (int m = 0; m < 8; ++m) {   // ascending code within lane
            const float sc = hv[m] - acc[j][m];
            const int code = cbase + m * 64 + lane;
            if (sc < s) { s = sc; bi = code; }
        }
        #pragma unroll
        for (int off = 32; off; off >>= 1) {
            const float os = __shfl_xor(s, off);
            const int oi = __shfl_xor(bi, off);
            if (os < s || (os == s && oi < bi)) { s = os; bi = oi; }
        }
        if (lane == 0) {
            const int token = token0 + j;
            bs[sp * Ntok + token] = s;
            bia[sp * Ntok + token] = bi;
        }
    }
}

__global__ __launch_bounds__(256) void vq_final(const float* __restrict__ emb,
                                                const float* __restrict__ bs,
                                                const int* __restrict__ bia,
                                                float* __restrict__ out, int Ntok) {
    const int token = blockIdx.x * 4 + (threadIdx.x >> 6);
    const int lane = threadIdx.x & 63;
    float best = 3.4e38f;
    int b = 0;
    #pragma unroll
    for (int s = 0; s < NSPLIT; ++s) {   // ascending split = ascending codes
        const float sc = bs[s * Ntok + token];
        const int ii = bia[s * Ntok + token];
        if (sc < best) { best = sc; b = ii; }
    }
    const float4* ef4 = reinterpret_cast<const float4*>(emb);
    float4* of4 = reinterpret_cast<float4*>(out);
    of4[(size_t)token * C4 + lane] = ef4[(size_t)b * C4 + lane];
}

extern "C" void kernel_launch(void* const* d_in, const int* in_sizes, int n_in,
                              void* d_out, int out_size, void* d_ws, size_t ws_size,
                              hipStream_t stream) {
    const float* z = (const float*)d_in[0];
    const float* emb = (const float*)d_in[1];
    float* out = (float*)d_out;

    const int N = in_sizes[0] / C;   // 16384 tokens
    const int K = in_sizes[1] / C;   // 8192 codes

    float* hn = (float*)d_ws;                 // K floats
    float* bs = hn + K;                       // NSPLIT*N floats
    int* bia = (int*)(bs + NSPLIT * N);       // NSPLIT*N ints (~2.1 MB total)

    vq_norms<<<K, 64, 0, stream>>>(emb, hn);
    vq_main<<<(N / BT) * NSPLIT, TPB, 0, stream>>>(z, emb, hn, bs, bia, N);
    vq_final<<<N / 4, 256, 0, stream>>>(emb, bs, bia, out, N);
}

// Round 6
// 610.403 us; speedup vs baseline: 17.2428x; 2.2293x over previous
//
#include <hip/hip_runtime.h>

// VQ nearest-codebook via split-bf16 MFMA GEMM + fp32 rescue.
// score(n,k) = 0.5*|e_k|^2 - z_n.e_k (monotone in squared distance)
//
// x = hi + lo (hi=bf16(x), lo=bf16(x-hi)); z.e ~ zhi.ehi + zlo.ehi + zhi.elo
// -> one bf16 GEMM, K=768, fp32 MFMA accum. Pass-1 emits top-2 per
// (token, 128-code slab); vq_pick rescores near-ties (tau=0.0625) in fp32.
//
// kernels: vq_norms (exact 0.5|e|^2), vq_split (fp32 -> bf16 hi/lo),
//          vq_gemm (m97-style 128x128 tile, swizzled LDS), vq_pick.

typedef unsigned short ushort;
typedef __attribute__((ext_vector_type(8))) short short8;
typedef __attribute__((ext_vector_type(4))) float f32x4;

#define C 256
#define MTOK 16384
#define NCODE 8192
#define BM 128
#define BN 128
#define BK 64
#define NSLAB (NCODE / BN)   // 64

__device__ __forceinline__ ushort bf16_rne(float x) {
    unsigned u = __float_as_uint(x);
    return (ushort)((u + 0x7FFFu + ((u >> 16) & 1u)) >> 16);
}

__device__ __forceinline__ bool lexlt(float as, int ai, float bs, int bi) {
    return as < bs || (as == bs && ai < bi);
}

// top2 (s1,i1,s2,i2) <- top2 of {self sorted pair, other sorted pair}
__device__ __forceinline__ void merge2(float& s1, int& i1, float& s2, int& i2,
                                       float os1, int oi1, float os2, int oi2) {
    if (lexlt(os1, oi1, s1, i1)) {
        float ns2; int ni2;
        if (lexlt(s1, i1, os2, oi2)) { ns2 = s1; ni2 = i1; }
        else                         { ns2 = os2; ni2 = oi2; }
        s2 = ns2; i2 = ni2; s1 = os1; i1 = oi1;
    } else if (lexlt(os1, oi1, s2, i2)) {
        s2 = os1; i2 = oi1;
    }
}

__device__ __forceinline__ void gload_lds16(const ushort* g, ushort* l) {
    __builtin_amdgcn_global_load_lds(
        (const __attribute__((address_space(1))) unsigned int*)g,
        (__attribute__((address_space(3))) unsigned int*)l, 16, 0, 0);
}

__global__ __launch_bounds__(64) void vq_norms(const float* __restrict__ emb,
                                               float* __restrict__ hn) {
    const int k = blockIdx.x;
    const int lane = threadIdx.x;
    const float4 v = *reinterpret_cast<const float4*>(emb + (size_t)k * C + lane * 4);
    float s = v.x * v.x + v.y * v.y + v.z * v.z + v.w * v.w;
    #pragma unroll
    for (int off = 32; off; off >>= 1) s += __shfl_down(s, off);
    if (lane == 0) hn[k] = 0.5f * s;
}

__global__ __launch_bounds__(256) void vq_split(const float* __restrict__ src,
                                                ushort* __restrict__ hi,
                                                ushort* __restrict__ lo, int n4) {
    typedef __attribute__((ext_vector_type(4))) ushort us4;
    const float4* s4 = reinterpret_cast<const float4*>(src);
    us4* h4 = reinterpret_cast<us4*>(hi);
    us4* l4 = reinterpret_cast<us4*>(lo);
    for (int i = blockIdx.x * 256 + threadIdx.x; i < n4; i += gridDim.x * 256) {
        const float4 v = s4[i];
        us4 h, l;
        float f[4] = {v.x, v.y, v.z, v.w};
        #pragma unroll
        for (int j = 0; j < 4; ++j) {
            const ushort hb = bf16_rne(f[j]);
            const float hf = __uint_as_float((unsigned)hb << 16);
            h[j] = hb;
            l[j] = bf16_rne(f[j] - hf);
        }
        h4[i] = h;
        l4[i] = l;
    }
}

__global__ __launch_bounds__(256) void vq_gemm(
    const ushort* __restrict__ zhi, const ushort* __restrict__ zlo,
    const ushort* __restrict__ ehi, const ushort* __restrict__ elo,
    const float* __restrict__ hn, float4* __restrict__ slab) {
    __shared__ ushort At[BM * BK];   // 16 KB, swizzled addressing
    __shared__ ushort Bt[BN * BK];   // 16 KB

    const int tid = threadIdx.x;
    const int lane = tid & 63;
    const int wid = __builtin_amdgcn_readfirstlane(tid >> 6);
    const int wr = wid >> 1, wc = wid & 1;
    const int mbase = blockIdx.x * BM;
    const int nb = blockIdx.y;
    const int nbase = nb * BN;

    // staging geometry: call i covers 32 rows; wave covers 8 rows (1 KB)
    const int srow = wid * 8 + (lane >> 3);      // + i*32
    const int schunk = (lane & 7) ^ (lane >> 3); // pre-swizzled source chunk

    f32x4 acc[4][4];
    #pragma unroll
    for (int a = 0; a < 4; ++a)
        #pragma unroll
        for (int b = 0; b < 4; ++b) acc[a][b] = (f32x4){0.f, 0.f, 0.f, 0.f};

    #pragma unroll 1
    for (int seg = 0; seg < 3; ++seg) {
        const ushort* As = (seg == 1) ? zlo : zhi;
        const ushort* Bs = (seg == 2) ? elo : ehi;
        #pragma unroll 1
        for (int kk = 0; kk < C / BK; ++kk) {
            const int k0 = kk * BK;
            __syncthreads();   // previous iteration's reads done
            #pragma unroll
            for (int i = 0; i < 4; ++i) {
                const int row = i * 32 + srow;
                gload_lds16(As + (size_t)(mbase + row) * C + k0 + schunk * 8,
                            &At[(i * 32 + wid * 8) * BK]);
            }
            #pragma unroll
            for (int i = 0; i < 4; ++i) {
                const int row = i * 32 + srow;
                gload_lds16(Bs + (size_t)(nbase + row) * C + k0 + schunk * 8,
                            &Bt[(i * 32 + wid * 8) * BK]);
            }
            __syncthreads();   // drains vmcnt (compiler) + barrier

            #pragma unroll
            for (int h = 0; h < 2; ++h) {
                short8 a[4], b[4];
                #pragma unroll
                for (int f = 0; f < 4; ++f) {
                    const int ar = wr * 64 + f * 16 + (lane & 15);
                    const int ag = h * 4 + (lane >> 4);
                    a[f] = *reinterpret_cast<const short8*>(
                        &At[ar * BK + ((ag ^ (ar & 7)) * 8)]);
                    const int br = wc * 64 + f * 16 + (lane & 15);
                    b[f] = *reinterpret_cast<const short8*>(
                        &Bt[br * BK + ((ag ^ (br & 7)) * 8)]);
                }
                #pragma unroll
                for (int fi = 0; fi < 4; ++fi)
                    #pragma unroll
                    for (int fj = 0; fj < 4; ++fj)
                        acc[fi][fj] = __builtin_amdgcn_mfma_f32_16x16x32_bf16(
                            a[fi], b[fj], acc[fi][fj], 0, 0, 0);
            }
        }
    }

    // epilogue: per-token top-2 over this block's 128 codes
    const int ng0 = nbase + wc * 64 + (lane & 15);
    float hv[4];
    #pragma unroll
    for (int fj = 0; fj < 4; ++fj) hv[fj] = hn[ng0 + fj * 16];

    __syncthreads();                         // all LDS reads done
    float* tl = reinterpret_cast<float*>(At);  // [128 m][2 wc][4 f] overlay

    #pragma unroll
    for (int fi = 0; fi < 4; ++fi) {
        #pragma unroll
        for (int r = 0; r < 4; ++r) {
            float s1 = 3.4e38f, s2 = 3.4e38f;
            int i1 = 0x7fffffff, i2 = 0x7fffffff;
            #pragma unroll
            for (int fj = 0; fj < 4; ++fj) {   // ascending code id
                const float sc = hv[fj] - acc[fi][fj][r];
                const int id = ng0 + fj * 16;
                if (lexlt(sc, id, s1, i1)) { s2 = s1; i2 = i1; s1 = sc; i1 = id; }
                else if (lexlt(sc, id, s2, i2)) { s2 = sc; i2 = id; }
            }
            #pragma unroll
            for (int off = 1; off <= 8; off <<= 1) {   // within 16-lane subgroup
                const float os1 = __shfl_xor(s1, off), os2 = __shfl_xor(s2, off);
                const int oi1 = __shfl_xor(i1, off), oi2 = __shfl_xor(i2, off);
                merge2(s1, i1, s2, i2, os1, oi1, os2, oi2);
            }
            if ((lane & 15) == 0) {
                const int m = wr * 64 + fi * 16 + (lane >> 4) * 4 + r;
                float* p = &tl[(m * 2 + wc) * 4];
                p[0] = s1; p[1] = __int_as_float(i1);
                p[2] = s2; p[3] = __int_as_float(i2);
            }
        }
    }
    __syncthreads();

    if (tid < BM) {
        const float* p0 = &tl[(tid * 2 + 0) * 4];
        const float* p1 = &tl[(tid * 2 + 1) * 4];
        float s1 = p0[0], s2 = p0[2];
        int i1 = __float_as_int(p0[1]), i2 = __float_as_int(p0[3]);
        merge2(s1, i1, s2, i2, p1[0], __float_as_int(p1[1]),
               p1[2], __float_as_int(p1[3]));
        const int token = mbase + tid;
        slab[(size_t)token * NSLAB + nb] =
            (float4){s1, __int_as_float(i1), s2, __int_as_float(i2)};
    }
}

__global__ __launch_bounds__(256) void vq_pick(
    const float* __restrict__ z, const float* __restrict__ emb,
    const float4* __restrict__ slab, float* __restrict__ out) {
    const int token = blockIdx.x * 4 + (threadIdx.x >> 6);
    const int lane = threadIdx.x & 63;

    const float4 c = slab[(size_t)token * NSLAB + lane];
    const float cs1 = c.x, cs2 = c.z;
    const int ci1 = __float_as_int(c.y), ci2 = __float_as_int(c.w);

    float bs = cs1;
    int bi = ci1;
    #pragma unroll
    for (int off = 32; off; off >>= 1) {
        const float os = __shfl_xor(bs, off);
        const int oi = __shfl_xor(bi, off);
        if (lexlt(os, oi, bs, bi)) { bs = os; bi = oi; }
    }

    const float tau = 0.0625f;
    const unsigned long long m1 = __ballot(cs1 <= bs + tau);
    const unsigned long long m2 = __ballot(cs2 <= bs + tau);
    int winner = bi;

    if (__popcll(m1) + __popcll(m2) > 1) {
        const float4 z4 = *reinterpret_cast<const float4*>(
            z + (size_t)token * C + lane * 4);
        float best = 3.4e38f;
        int besti = 0x7fffffff;
        #pragma unroll 1
        for (int pass = 0; pass < 2; ++pass) {
            unsigned long long mm = pass ? m2 : m1;
            while (mm) {
                const int l = __builtin_ctzll(mm);
                mm &= mm - 1;
                const int cidx = __shfl(pass ? ci2 : ci1, l);
                const float4 e4 = *reinterpret_cast<const float4*>(
                    emb + (size_t)cidx * C + lane * 4);
                float p = 0.5f * (e4.x * e4.x + e4.y * e4.y + e4.z * e4.z +
                                  e4.w * e4.w)
                        - (z4.x * e4.x + z4.y * e4.y + z4.z * e4.z + z4.w * e4.w);
                #pragma unroll
                for (int off = 32; off; off >>= 1) p += __shfl_xor(p, off);
                if (lexlt(p, cidx, best, besti)) { best = p; besti = cidx; }
            }
        }
        winner = besti;
    }

    const float4 v = *reinterpret_cast<const float4*>(
        emb + (size_t)winner * C + lane * 4);
    *reinterpret_cast<float4*>(out + (size_t)token * C + lane * 4) = v;
}

extern "C" void kernel_launch(void* const* d_in, const int* in_sizes, int n_in,
                              void* d_out, int out_size, void* d_ws, size_t ws_size,
                              hipStream_t stream) {
    const float* z = (const float*)d_in[0];
    const float* emb = (const float*)d_in[1];
    float* out = (float*)d_out;

    char* w = (char*)d_ws;
    float* hn = (float*)w;            w += (size_t)NCODE * 4;
    ushort* zhi = (ushort*)w;         w += (size_t)MTOK * C * 2;
    ushort* zlo = (ushort*)w;         w += (size_t)MTOK * C * 2;
    ushort* ehi = (ushort*)w;         w += (size_t)NCODE * C * 2;
    ushort* elo = (ushort*)w;         w += (size_t)NCODE * C * 2;
    float4* slab = (float4*)w;        // MTOK*NSLAB*16B = 16.8 MB

    vq_norms<<<NCODE, 64, 0, stream>>>(emb, hn);
    vq_split<<<1024, 256, 0, stream>>>(z, zhi, zlo, MTOK * C / 4);
    vq_split<<<512, 256, 0, stream>>>(emb, ehi, elo, NCODE * C / 4);

    dim3 grid(MTOK / BM, NCODE / BN);
    vq_gemm<<<grid, 256, 0, stream>>>(zhi, zlo, ehi, elo, hn, slab);

    vq_pick<<<MTOK / 4, 256, 0, stream>>>(z, emb, slab, out);
}